// Round 9
// baseline (222.543 us; speedup 1.0000x reference)
//
#include <hip/hip_runtime.h>
#include <math.h>

#define BATCH  8
#define SEQLEN 4096
#define HID    1024
#define STATE  64
#define NC     16
#define TC     (SEQLEN / NC)   // 256 steps per chunk
#define TT     32              // time rows per LDS tile
#define NTILE  (TC / TT)       // 8 tiles per chunk
#define DBLK   64              // channels per block (4 waves x 16)
#define NS     16              // states per lane (4 lanes per channel)
#define NP     8               // f32x2 pairs per lane

typedef float f32x2 __attribute__((ext_vector_type(2)));

// ws layout (bytes):
//   pa: [0, 256K)  pw: [256K, 512K)  pE: [512K, 768K)
//   zl: [1M, 1M + (NC-1)*BATCH*HID*STATE*4)  = 30 MB of chunk states
#define WS_PA 0
#define WS_PW (256 * 1024)
#define WS_PE (512 * 1024)
#define WS_ZL (1024 * 1024)

// async global->LDS, 16B per lane. LDS dest is wave-uniform base + lane*16.
__device__ __forceinline__ void gload_lds16(const float* g, float* l) {
    __builtin_amdgcn_global_load_lds((const __attribute__((address_space(1))) void*)g,
                                     (__attribute__((address_space(3))) void*)l,
                                     16, 0, 0);
}

// quad-lane sum via DPP (pure VALU; 4 lanes per channel)
__device__ __forceinline__ float quad_reduce_add(float y) {
    int t = __builtin_amdgcn_mov_dpp(__builtin_bit_cast(int, y), 0xB1, 0xF, 0xF, true); // [1,0,3,2]
    y += __builtin_bit_cast(float, t);
    t = __builtin_amdgcn_mov_dpp(__builtin_bit_cast(int, y), 0x4E, 0xF, 0xF, true);     // [2,3,0,1]
    y += __builtin_bit_cast(float, t);
    return y;
}

// ---------------------------------------------------------------- K0: params
__global__ void k0_params(const float* __restrict__ A, const float* __restrict__ Bm,
                          const float* __restrict__ C, const float* __restrict__ dt,
                          float* __restrict__ pa, float* __restrict__ pw,
                          float* __restrict__ pE) {
    int i = blockIdx.x * 256 + threadIdx.x;
    if (i >= HID * STATE) return;
    int n = i & (STATE - 1);
    float aexp = expf(A[i]);
    float dtn  = dt[n];
    float a    = expf(-aexp * dtn);
    pa[i] = a;
    pw[i] = C[i] * (Bm[i] * (1.0f - a) / aexp);   // C * dB
    pE[i] = expf(-aexp * dtn * (float)TC);        // a^TC (chunk transition)
}

// ------------------------------------------- K1: chunk-local end states (z-space)
// block = (dset64, b, chunk); 4 waves x 16 channels; u staged in LDS tiles.
// VGPR need ~48 -> (256,6) caps at ~85: no spill risk, 6 blocks/CU resident.
__global__ __launch_bounds__(256, 6) void k1_locals(const float* __restrict__ u,
                                                    const float* __restrict__ pa,
                                                    float* __restrict__ zl) {
    __shared__ float utile[2][TT * DBLK];
    int bid  = blockIdx.x;
    int dset = bid & 15;
    int b    = (bid >> 4) & 7;
    int c    = bid >> 7;                       // chunk 0..NC-2
    int w    = threadIdx.x >> 6;
    int lane = threadIdx.x & 63;
    int dl   = lane >> 2, p = lane & 3;
    int d    = dset * DBLK + w * 16 + dl;

    f32x2 a2[NP], z2[NP];
    {
        const f32x2* pap = (const f32x2*)(pa + (size_t)d * STATE + p * NS);
        #pragma unroll
        for (int j = 0; j < NP; j++) a2[j] = pap[j];
    }
    #pragma unroll
    for (int j = 0; j < NP; j++) { z2[j].x = 0.f; z2[j].y = 0.f; }

    const char* ubase = (const char*)(u + ((size_t)b * SEQLEN + (size_t)c * TC) * HID
                                        + (size_t)dset * DBLK);

    // issue tile `t` into buffer `buf`: 2 x 16B per lane, coalesced 256B rows
    #define ISSUE_TILE(t, buf)                                                        \
        {                                                                             \
            _Pragma("unroll")                                                         \
            for (int k = 0; k < 2; k++) {                                             \
                int off = w * 2048 + k * 1024 + lane * 16;   /* byte in 8KB tile */   \
                int row = off >> 8;                                                   \
                int col = off & 255;                                                  \
                const float* src = (const float*)(ubase + ((size_t)((t) * TT + row)) * (HID * 4) + col); \
                float* dst = &utile[buf][w * 512 + k * 256];                           \
                gload_lds16(src, dst);                                                \
            }                                                                         \
        }

    ISSUE_TILE(0, 0);
    __syncthreads();
    int cur = 0;
    for (int tile = 0; tile < NTILE; ++tile) {
        if (tile + 1 < NTILE) ISSUE_TILE(tile + 1, cur ^ 1);
        const float* ut = &utile[cur][w * 16 + dl];
        #pragma unroll
        for (int r = 0; r < TT; r++) {
            float uss = ut[r * DBLK];                 // ds_read_b32, 4-lane broadcast
            f32x2 us; us.x = uss; us.y = uss;
            #pragma unroll
            for (int j = 0; j < NP; j++)
                z2[j] = __builtin_elementwise_fma(a2[j], z2[j], us);
        }
        __syncthreads();                              // drains vmcnt too
        cur ^= 1;
    }

    f32x2* zp = (f32x2*)(zl + (((size_t)c * BATCH + b) * HID + d) * STATE + p * NS);
    #pragma unroll
    for (int j = 0; j < NP; j++) zp[j] = z2[j];
}

// ---------------------------------- K2: prefix scan over chunks (in-place in zl)
__global__ void k2_scan(const float* __restrict__ pE, float* __restrict__ zl) {
    int i  = blockIdx.x * 256 + threadIdx.x;            // (b,d,n)
    int dn = i & (HID * STATE - 1);
    float E = pE[dn];
    size_t stride = (size_t)BATCH * HID * STATE;
    float g = zl[i];                                     // slot0 already global
    for (int c = 1; c < NC - 1; c++) {
        float v = zl[i + c * stride];
        g = fmaf(E, g, v);
        zl[i + c * stride] = g;                          // slot c = global end of chunk c
    }
}

// --------------------------------------------------- K3: main pass with outputs
// VGPR need ~48 -> (256,6): up to 24 waves/CU (was bound-limited to 12 at (256,3)).
__global__ __launch_bounds__(256, 6) void k3_main(const float* __restrict__ u,
                                                  const float* __restrict__ Dv,
                                                  const float* __restrict__ pa,
                                                  const float* __restrict__ pw,
                                                  const float* __restrict__ zl,
                                                  float* __restrict__ out) {
    __shared__ float utile[2][TT * DBLK];
    int bid  = blockIdx.x;
    int dset = bid & 15;
    int b    = (bid >> 4) & 7;
    int c    = bid >> 7;                       // chunk 0..NC-1
    int w    = threadIdx.x >> 6;
    int lane = threadIdx.x & 63;
    int dl   = lane >> 2, p = lane & 3;
    int d    = dset * DBLK + w * 16 + dl;

    f32x2 a2[NP], w2[NP], z2[NP];
    {
        const f32x2* pap = (const f32x2*)(pa + (size_t)d * STATE + p * NS);
        const f32x2* pwp = (const f32x2*)(pw + (size_t)d * STATE + p * NS);
        #pragma unroll
        for (int j = 0; j < NP; j++) { a2[j] = pap[j]; w2[j] = pwp[j]; }
    }
    if (c == 0) {
        #pragma unroll
        for (int j = 0; j < NP; j++) { z2[j].x = 0.f; z2[j].y = 0.f; }
    } else {
        size_t stride = (size_t)BATCH * HID * STATE;
        const f32x2* zp = (const f32x2*)(zl + (size_t)(c - 1) * stride +
                                         ((size_t)b * HID + d) * STATE + p * NS);
        #pragma unroll
        for (int j = 0; j < NP; j++) z2[j] = zp[j];
    }

    float dvd = Dv[d];
    const char* ubase = (const char*)(u + ((size_t)b * SEQLEN + (size_t)c * TC) * HID
                                        + (size_t)dset * DBLK);
    float* po = out + ((size_t)b * SEQLEN + (size_t)c * TC) * HID + d;

    ISSUE_TILE(0, 0);
    __syncthreads();
    int cur = 0;
    for (int tile = 0; tile < NTILE; ++tile) {
        if (tile + 1 < NTILE) ISSUE_TILE(tile + 1, cur ^ 1);
        const float* ut = &utile[cur][w * 16 + dl];
        float* po_t = po + (size_t)tile * TT * HID;
        #pragma unroll
        for (int r = 0; r < TT; r++) {
            float uss = ut[r * DBLK];                 // ds_read_b32, 4-lane broadcast
            f32x2 us; us.x = uss; us.y = uss;
            #pragma unroll
            for (int j = 0; j < NP; j++)
                z2[j] = __builtin_elementwise_fma(a2[j], z2[j], us);
            f32x2 acc0 = z2[0] * w2[0];
            f32x2 acc1 = z2[1] * w2[1];
            #pragma unroll
            for (int j = 2; j < NP; j += 2) {
                acc0 = __builtin_elementwise_fma(z2[j + 0], w2[j + 0], acc0);
                acc1 = __builtin_elementwise_fma(z2[j + 1], w2[j + 1], acc1);
            }
            acc0 += acc1;
            float y = acc0.x + acc0.y;
            y = quad_reduce_add(y);                   // sum 4 lanes of this channel
            po_t[(size_t)r * HID] = fmaf(dvd, uss, y);
        }
        __syncthreads();
        cur ^= 1;
    }
}

extern "C" void kernel_launch(void* const* d_in, const int* in_sizes, int n_in,
                              void* d_out, int out_size, void* d_ws, size_t ws_size,
                              hipStream_t stream) {
    const float* u  = (const float*)d_in[0];
    const float* A  = (const float*)d_in[1];
    const float* Bm = (const float*)d_in[2];
    const float* C  = (const float*)d_in[3];
    const float* Dv = (const float*)d_in[4];
    const float* dt = (const float*)d_in[5];
    float* out = (float*)d_out;

    char* ws = (char*)d_ws;
    float* pa = (float*)(ws + WS_PA);
    float* pw = (float*)(ws + WS_PW);
    float* pE = (float*)(ws + WS_PE);
    float* zl = (float*)(ws + WS_ZL);

    k0_params<<<(HID * STATE) / 256, 256, 0, stream>>>(A, Bm, C, dt, pa, pw, pE);
    // k1: 16 dsets * 8 b * 15 chunks
    k1_locals<<<16 * 8 * (NC - 1), 256, 0, stream>>>(u, pa, zl);
    k2_scan<<<(BATCH * HID * STATE) / 256, 256, 0, stream>>>(pE, zl);
    // k3: 16 dsets * 8 b * 16 chunks
    k3_main<<<16 * 8 * NC, 256, 0, stream>>>(u, Dv, pa, pw, zl, out);
}

// Round 10
// 173.947 us; speedup vs baseline: 1.2794x; 1.2794x over previous
//
#include <hip/hip_runtime.h>
#include <math.h>

#define BATCH  8
#define SEQLEN 4096
#define HID    1024
#define STATE  64
#define NC     16
#define TC     (SEQLEN / NC)   // 256 steps per chunk
#define TT     32              // time rows per LDS tile
#define NTILE  (TC / TT)       // 8 tiles per chunk
#define DBLK   64              // channels per block (4 waves x 16)
#define NS     16              // states per lane (4 lanes per channel)
#define NP     8               // f32x2 pairs per lane
#define RB     8               // reduce/store batch within a tile

typedef float f32x2 __attribute__((ext_vector_type(2)));

// ws layout (bytes):
//   pa: [0, 256K)  pw: [256K, 512K)  pE: [512K, 768K)
//   zl: [1M, 1M + (NC-1)*BATCH*HID*STATE*4)  = 30 MB of chunk states
#define WS_PA 0
#define WS_PW (256 * 1024)
#define WS_PE (512 * 1024)
#define WS_ZL (1024 * 1024)

// async global->LDS, 16B per lane. LDS dest is wave-uniform base + lane*16.
__device__ __forceinline__ void gload_lds16(const float* g, float* l) {
    __builtin_amdgcn_global_load_lds((const __attribute__((address_space(1))) void*)g,
                                     (__attribute__((address_space(3))) void*)l,
                                     16, 0, 0);
}

// quad-lane sum via DPP (pure VALU; 4 lanes per channel)
__device__ __forceinline__ float quad_reduce_add(float y) {
    int t = __builtin_amdgcn_mov_dpp(__builtin_bit_cast(int, y), 0xB1, 0xF, 0xF, true); // [1,0,3,2]
    y += __builtin_bit_cast(float, t);
    t = __builtin_amdgcn_mov_dpp(__builtin_bit_cast(int, y), 0x4E, 0xF, 0xF, true);     // [2,3,0,1]
    y += __builtin_bit_cast(float, t);
    return y;
}

// ---------------------------------------------------------------- K0: params
__global__ void k0_params(const float* __restrict__ A, const float* __restrict__ Bm,
                          const float* __restrict__ C, const float* __restrict__ dt,
                          float* __restrict__ pa, float* __restrict__ pw,
                          float* __restrict__ pE) {
    int i = blockIdx.x * 256 + threadIdx.x;
    if (i >= HID * STATE) return;
    int n = i & (STATE - 1);
    float aexp = expf(A[i]);
    float dtn  = dt[n];
    float a    = expf(-aexp * dtn);
    pa[i] = a;
    pw[i] = C[i] * (Bm[i] * (1.0f - a) / aexp);   // C * dB
    pE[i] = expf(-aexp * dtn * (float)TC);        // a^TC (chunk transition)
}

// ------------------------------------------- K1: chunk-local end states (z-space)
// (256,3): BW-bound streamer — more residency HURTS HBM efficiency (round-9).
__global__ __launch_bounds__(256, 3) void k1_locals(const float* __restrict__ u,
                                                    const float* __restrict__ pa,
                                                    float* __restrict__ zl) {
    __shared__ float utile[2][TT * DBLK];
    int bid  = blockIdx.x;
    int dset = bid & 15;
    int b    = (bid >> 4) & 7;
    int c    = bid >> 7;                       // chunk 0..NC-2
    int w    = threadIdx.x >> 6;
    int lane = threadIdx.x & 63;
    int dl   = lane >> 2, p = lane & 3;
    int d    = dset * DBLK + w * 16 + dl;

    f32x2 a2[NP], z2[NP];
    {
        const f32x2* pap = (const f32x2*)(pa + (size_t)d * STATE + p * NS);
        #pragma unroll
        for (int j = 0; j < NP; j++) a2[j] = pap[j];
    }
    #pragma unroll
    for (int j = 0; j < NP; j++) { z2[j].x = 0.f; z2[j].y = 0.f; }

    const char* ubase = (const char*)(u + ((size_t)b * SEQLEN + (size_t)c * TC) * HID
                                        + (size_t)dset * DBLK);

    // issue tile `t` into buffer `buf`: 2 x 16B per lane, coalesced 256B rows
    #define ISSUE_TILE(t, buf)                                                        \
        {                                                                             \
            _Pragma("unroll")                                                         \
            for (int k = 0; k < 2; k++) {                                             \
                int off = w * 2048 + k * 1024 + lane * 16;   /* byte in 8KB tile */   \
                int row = off >> 8;                                                   \
                int col = off & 255;                                                  \
                const float* src = (const float*)(ubase + ((size_t)((t) * TT + row)) * (HID * 4) + col); \
                float* dst = &utile[buf][w * 512 + k * 256];                           \
                gload_lds16(src, dst);                                                \
            }                                                                         \
        }

    ISSUE_TILE(0, 0);
    __syncthreads();
    int cur = 0;
    for (int tile = 0; tile < NTILE; ++tile) {
        if (tile + 1 < NTILE) ISSUE_TILE(tile + 1, cur ^ 1);
        const float* ut = &utile[cur][w * 16 + dl];
        #pragma unroll
        for (int r = 0; r < TT; r++) {
            float uss = ut[r * DBLK];                 // ds_read_b32, 4-lane broadcast
            f32x2 us; us.x = uss; us.y = uss;
            #pragma unroll
            for (int j = 0; j < NP; j++)
                z2[j] = __builtin_elementwise_fma(a2[j], z2[j], us);
        }
        __syncthreads();                              // drains vmcnt too
        cur ^= 1;
    }

    f32x2* zp = (f32x2*)(zl + (((size_t)c * BATCH + b) * HID + d) * STATE + p * NS);
    #pragma unroll
    for (int j = 0; j < NP; j++) zp[j] = z2[j];
}

// ---------------------------------- K2: prefix scan over chunks (in-place in zl)
__global__ void k2_scan(const float* __restrict__ pE, float* __restrict__ zl) {
    int i  = blockIdx.x * 256 + threadIdx.x;            // (b,d,n)
    int dn = i & (HID * STATE - 1);
    float E = pE[dn];
    size_t stride = (size_t)BATCH * HID * STATE;
    float g = zl[i];                                     // slot0 already global
    for (int c = 1; c < NC - 1; c++) {
        float v = zl[i + c * stride];
        g = fmaf(E, g, v);
        zl[i + c * stride] = g;                          // slot c = global end of chunk c
    }
}

// --------------------------------------------------- K3: main pass with outputs
// (256,3): proven best. Batched tail: RB independent DPP-reduce chains pipeline
// the DPP hazard gaps; stores issue back-to-back.
__global__ __launch_bounds__(256, 3) void k3_main(const float* __restrict__ u,
                                                  const float* __restrict__ Dv,
                                                  const float* __restrict__ pa,
                                                  const float* __restrict__ pw,
                                                  const float* __restrict__ zl,
                                                  float* __restrict__ out) {
    __shared__ float utile[2][TT * DBLK];
    int bid  = blockIdx.x;
    int dset = bid & 15;
    int b    = (bid >> 4) & 7;
    int c    = bid >> 7;                       // chunk 0..NC-1
    int w    = threadIdx.x >> 6;
    int lane = threadIdx.x & 63;
    int dl   = lane >> 2, p = lane & 3;
    int d    = dset * DBLK + w * 16 + dl;

    f32x2 a2[NP], w2[NP], z2[NP];
    {
        const f32x2* pap = (const f32x2*)(pa + (size_t)d * STATE + p * NS);
        const f32x2* pwp = (const f32x2*)(pw + (size_t)d * STATE + p * NS);
        #pragma unroll
        for (int j = 0; j < NP; j++) { a2[j] = pap[j]; w2[j] = pwp[j]; }
    }
    if (c == 0) {
        #pragma unroll
        for (int j = 0; j < NP; j++) { z2[j].x = 0.f; z2[j].y = 0.f; }
    } else {
        size_t stride = (size_t)BATCH * HID * STATE;
        const f32x2* zp = (const f32x2*)(zl + (size_t)(c - 1) * stride +
                                         ((size_t)b * HID + d) * STATE + p * NS);
        #pragma unroll
        for (int j = 0; j < NP; j++) z2[j] = zp[j];
    }

    float dvd = Dv[d];
    const char* ubase = (const char*)(u + ((size_t)b * SEQLEN + (size_t)c * TC) * HID
                                        + (size_t)dset * DBLK);
    float* po = out + ((size_t)b * SEQLEN + (size_t)c * TC) * HID + d;

    ISSUE_TILE(0, 0);
    __syncthreads();
    int cur = 0;
    for (int tile = 0; tile < NTILE; ++tile) {
        if (tile + 1 < NTILE) ISSUE_TILE(tile + 1, cur ^ 1);
        const float* ut = &utile[cur][w * 16 + dl];
        float* po_t = po + (size_t)tile * TT * HID;
        #pragma unroll
        for (int r0 = 0; r0 < TT; r0 += RB) {
            float ylane[RB], usv[RB];
            // compute phase: pure FMA issue, per-lane partials for RB steps
            #pragma unroll
            for (int i = 0; i < RB; i++) {
                float uss = ut[(r0 + i) * DBLK];      // ds_read_b32, 4-lane broadcast
                usv[i] = uss;
                f32x2 us; us.x = uss; us.y = uss;
                #pragma unroll
                for (int j = 0; j < NP; j++)
                    z2[j] = __builtin_elementwise_fma(a2[j], z2[j], us);
                f32x2 acc0 = z2[0] * w2[0];
                f32x2 acc1 = z2[1] * w2[1];
                #pragma unroll
                for (int j = 2; j < NP; j += 2) {
                    acc0 = __builtin_elementwise_fma(z2[j + 0], w2[j + 0], acc0);
                    acc1 = __builtin_elementwise_fma(z2[j + 1], w2[j + 1], acc1);
                }
                acc0 += acc1;
                ylane[i] = acc0.x + acc0.y;
            }
            // reduce phase: RB independent DPP chains (hazards pipeline away)
            #pragma unroll
            for (int i = 0; i < RB; i++) ylane[i] = quad_reduce_add(ylane[i]);
            // store phase
            #pragma unroll
            for (int i = 0; i < RB; i++)
                po_t[(size_t)(r0 + i) * HID] = fmaf(dvd, usv[i], ylane[i]);
        }
        __syncthreads();
        cur ^= 1;
    }
}

extern "C" void kernel_launch(void* const* d_in, const int* in_sizes, int n_in,
                              void* d_out, int out_size, void* d_ws, size_t ws_size,
                              hipStream_t stream) {
    const float* u  = (const float*)d_in[0];
    const float* A  = (const float*)d_in[1];
    const float* Bm = (const float*)d_in[2];
    const float* C  = (const float*)d_in[3];
    const float* Dv = (const float*)d_in[4];
    const float* dt = (const float*)d_in[5];
    float* out = (float*)d_out;

    char* ws = (char*)d_ws;
    float* pa = (float*)(ws + WS_PA);
    float* pw = (float*)(ws + WS_PW);
    float* pE = (float*)(ws + WS_PE);
    float* zl = (float*)(ws + WS_ZL);

    k0_params<<<(HID * STATE) / 256, 256, 0, stream>>>(A, Bm, C, dt, pa, pw, pE);
    // k1: 16 dsets * 8 b * 15 chunks
    k1_locals<<<16 * 8 * (NC - 1), 256, 0, stream>>>(u, pa, zl);
    k2_scan<<<(BATCH * HID * STATE) / 256, 256, 0, stream>>>(pE, zl);
    // k3: 16 dsets * 8 b * 16 chunks
    k3_main<<<16 * 8 * NC, 256, 0, stream>>>(u, Dv, pa, pw, zl, out);
}